// Round 1
// baseline (232.128 us; speedup 1.0000x reference)
//
#include <hip/hip_runtime.h>
#include <stdint.h>

#define DEMB 1024
#define NHEAD 16
#define DHEAD 64
#define SEQ 2048
#define MROWS 4096  // B*S

typedef __bf16 bf16x8 __attribute__((ext_vector_type(8)));
typedef float f32x4 __attribute__((ext_vector_type(4)));
typedef unsigned short u16;

#define LOG2E 1.44269504088896340736f

__device__ __forceinline__ u16 f2b(float f) {
  uint32_t u = __builtin_bit_cast(uint32_t, f);
  u += 0x7fffu + ((u >> 16) & 1u);
  return (u16)(u >> 16);
}

__device__ __forceinline__ f32x4 mfma16(bf16x8 a, bf16x8 b, f32x4 c) {
  return __builtin_amdgcn_mfma_f32_16x16x32_bf16(a, b, c, 0, 0, 0);
}

// global -> LDS direct (16B per lane). lds base must be wave-uniform; lane i
// lands at base + i*16. Global src is per-lane.
__device__ __forceinline__ void gload_lds16(const void* g, void* l) {
  __builtin_amdgcn_global_load_lds(
      (__attribute__((address_space(1))) unsigned int*)(g),
      (__attribute__((address_space(3))) unsigned int*)(l), 16, 0, 0);
}

__global__ void cvt_f32_bf16(const float* __restrict__ src, u16* __restrict__ dst, int n) {
  int idx = (blockIdx.x * blockDim.x + threadIdx.x) * 4;
  const int stride = gridDim.x * blockDim.x * 4;
  for (; idx < n; idx += stride) {
    float4 f = *(const float4*)(src + idx);
    ushort4 o;
    o.x = f2b(f.x); o.y = f2b(f.y); o.z = f2b(f.z); o.w = f2b(f.w);
    *(ushort4*)(dst + idx) = o;
  }
}

// NT GEMM: C[m,n] = sum_k A[m,k]*B[n,k] (+bias[n]).
// BM=BN=128, BK=64, 256 threads (4 waves, 2x2), each wave 64x64 (4x4 frags).
// LDS tiles [128 rows][64 cols] bf16 with XOR swizzle: byte-col ^= (row&7)<<4,
// realized via pre-swizzled global source columns (global_load_lds dest is linear).
// EPI==0: scatter to Q/K/V [B,H,S,Dh] bf16.  EPI==1: write fp32 C[m*N+n].
template <int EPI>
__global__ __launch_bounds__(256, 2) void gemm_nt(
    const u16* __restrict__ A, const u16* __restrict__ Bw,
    const float* __restrict__ bias, int K, int N,
    u16* __restrict__ q_out, u16* __restrict__ k_out, u16* __restrict__ v_out,
    float* __restrict__ f_out) {
  __shared__ __align__(16) u16 As[128 * 64];
  __shared__ __align__(16) u16 Bs[128 * 64];
  const int tid = threadIdx.x;
  const int w = tid >> 6;
  const int lane = tid & 63;
  const int wm = w >> 1, wn = w & 1;
  const int m0 = blockIdx.y * 128, n0 = blockIdx.x * 128;
  const int l16 = lane & 15, lg = lane >> 4;
  const int st_row = lane >> 3, st_slot = lane & 7;

  f32x4 acc[4][4] = {};

  for (int k0 = 0; k0 < K; k0 += 64) {
    // stage A and B tiles: 16KB each, 4 x 16B per thread per tile
#pragma unroll
    for (int i = 0; i < 4; ++i) {
      const int chunk = (w << 2) | i;        // 0..15, covers LDS bytes chunk*1024
      const int row = (chunk << 3) | st_row; // 0..127
      const int scol = (st_slot ^ (row & 7)) << 3; // pre-swizzled source column
      gload_lds16(A + (size_t)(m0 + row) * K + k0 + scol, (char*)As + (chunk << 10));
      gload_lds16(Bw + (size_t)(n0 + row) * K + k0 + scol, (char*)Bs + (chunk << 10));
    }
    __syncthreads();
#pragma unroll
    for (int ks = 0; ks < 2; ++ks) {
      bf16x8 af[4], bfr[4];
#pragma unroll
      for (int mi = 0; mi < 4; ++mi) {
        const int row = wm * 64 + mi * 16 + l16;
        const int cb = ((ks << 6) | (lg << 4)) ^ ((row & 7) << 4);
        af[mi] = *(const bf16x8*)((const char*)As + row * 128 + cb);
      }
#pragma unroll
      for (int ni = 0; ni < 4; ++ni) {
        const int row = wn * 64 + ni * 16 + l16;
        const int cb = ((ks << 6) | (lg << 4)) ^ ((row & 7) << 4);
        bfr[ni] = *(const bf16x8*)((const char*)Bs + row * 128 + cb);
      }
#pragma unroll
      for (int mi = 0; mi < 4; ++mi)
#pragma unroll
        for (int ni = 0; ni < 4; ++ni)
          acc[mi][ni] = mfma16(af[mi], bfr[ni], acc[mi][ni]);
    }
    __syncthreads();
  }

  // epilogue: D-frag mapping row=(lane>>4)*4+i, col=lane&15
#pragma unroll
  for (int ni = 0; ni < 4; ++ni) {
    const int n = n0 + wn * 64 + ni * 16 + l16;
    const float bv = bias[n];
    if (EPI == 0) {
      const int part = n >> 10;
      const int hh = (n >> 6) & 15;
      const int dh = n & 63;
      u16* dst = (part == 0) ? q_out : (part == 1) ? k_out : v_out;
#pragma unroll
      for (int mi = 0; mi < 4; ++mi) {
#pragma unroll
        for (int i = 0; i < 4; ++i) {
          const int m = m0 + wm * 64 + mi * 16 + (lg << 2) + i;
          const int bq = m >> 11, s = m & 2047;
          dst[((size_t)((bq << 4) | hh) * SEQ + s) * DHEAD + dh] = f2b(acc[mi][ni][i] + bv);
        }
      }
    } else {
#pragma unroll
      for (int mi = 0; mi < 4; ++mi)
#pragma unroll
        for (int i = 0; i < 4; ++i) {
          const int m = m0 + wm * 64 + mi * 16 + (lg << 2) + i;
          f_out[(size_t)m * N + n] = acc[mi][ni][i] + bv;
        }
    }
  }
}

// Flash attention, causal (runtime-switchable). Block = (q-tile of 64 rows, bh).
// 4 waves x 16 q-rows. KV tile = 64. K staged via swizzled global_load_lds;
// V transposed into swizzled LDS; P round-trips swizzled per-wave LDS.
__global__ __launch_bounds__(256, 4) void attn_fwd(
    const u16* __restrict__ Qb, const u16* __restrict__ Kb,
    const u16* __restrict__ Vb, u16* __restrict__ Ob,
    const int* __restrict__ amask) {
  __shared__ __align__(16) u16 Ks[64 * 64];
  __shared__ __align__(16) u16 Vt[64 * 64];
  __shared__ __align__(16) u16 Ps[4][16 * 64];
  const int tid = threadIdx.x;
  const int w = tid >> 6, lane = tid & 63;
  const int l16 = lane & 15, lg = lane >> 4;
  const int qi = blockIdx.x, bh = blockIdx.y;
  const int qblk0 = qi * 64;
  const size_t base = (size_t)bh * (SEQ * DHEAD);
  const bool causal = (amask[0] != 0);

  // Q fragments in registers (A-operand: row = lane%16, k = (lane/16)*8+e)
  bf16x8 qf[2];
  {
    const u16* qp = Qb + base + (size_t)(qblk0 + w * 16 + l16) * DHEAD + (lg << 3);
    qf[0] = *(const bf16x8*)qp;
    qf[1] = *(const bf16x8*)(qp + 32);
  }

  float mrow[4] = {-1e30f, -1e30f, -1e30f, -1e30f};
  float lrow[4] = {0.f, 0.f, 0.f, 0.f};
  f32x4 oacc[4] = {};
  const int st_row = lane >> 3, st_slot = lane & 7;
  const int ntiles = causal ? (qi + 1) : (SEQ / 64);

  for (int j = 0; j < ntiles; ++j) {
    // stage K tile [64][64] (8KB): 2 x 16B per thread, swizzled source
#pragma unroll
    for (int i = 0; i < 2; ++i) {
      const int chunk = (w << 1) | i;
      const int row = (chunk << 3) | st_row;
      const int scol = (st_slot ^ (row & 7)) << 3;
      gload_lds16(Kb + base + (size_t)(j * 64 + row) * DHEAD + scol, (char*)Ks + (chunk << 10));
    }
    // stage V transposed: Vt[d][kv], swizzled scalar writes
#pragma unroll
    for (int it = 0; it < 2; ++it) {
      const int vr = it * 32 + (tid >> 3);  // kv row
      const int c0 = (tid & 7) << 3;        // d col base
      u16 vals[8];
      *(uint4*)vals = *(const uint4*)(Vb + base + (size_t)(j * 64 + vr) * DHEAD + c0);
#pragma unroll
      for (int e = 0; e < 8; ++e) {
        const int rt = c0 + e;
        *(u16*)((char*)Vt + rt * 128 + ((vr << 1) ^ ((rt & 7) << 4))) = vals[e];
      }
    }
    __syncthreads();

    // S = Q K^T  (per wave: 16 q-rows x 64 kv)
    f32x4 sv[4];
#pragma unroll
    for (int nf = 0; nf < 4; ++nf) {
      const int row = nf * 16 + l16;
      const int sw = (row & 7) << 4;
      bf16x8 kf0 = *(const bf16x8*)((const char*)Ks + row * 128 + ((lg << 4) ^ sw));
      bf16x8 kf1 = *(const bf16x8*)((const char*)Ks + row * 128 + ((64 | (lg << 4)) ^ sw));
      f32x4 s = {};
      s = mfma16(qf[0], kf0, s);
      s = mfma16(qf[1], kf1, s);
      sv[nf] = s;
    }

    const bool diag = causal && (j == qi);
#pragma unroll
    for (int nf = 0; nf < 4; ++nf)
#pragma unroll
      for (int i = 0; i < 4; ++i) {
        float s = sv[nf][i] * 0.125f;  // 1/sqrt(64)
        if (diag) {
          const int qrow = (w << 4) + (lg << 2) + i;  // within block
          const int col = nf * 16 + l16;              // within tile
          if (col > qrow) s = -1e30f;
        }
        sv[nf][i] = s;
      }

    // row max (16-lane group shuffle reduce)
    float tmax[4];
#pragma unroll
    for (int i = 0; i < 4; ++i)
      tmax[i] = fmaxf(fmaxf(sv[0][i], sv[1][i]), fmaxf(sv[2][i], sv[3][i]));
#pragma unroll
    for (int d = 1; d < 16; d <<= 1)
#pragma unroll
      for (int i = 0; i < 4; ++i)
        tmax[i] = fmaxf(tmax[i], __shfl_xor(tmax[i], d));

    float corr[4];
#pragma unroll
    for (int i = 0; i < 4; ++i) {
      const float mnew = fmaxf(mrow[i], tmax[i]);
      corr[i] = exp2f((mrow[i] - mnew) * LOG2E);
      mrow[i] = mnew;
      lrow[i] *= corr[i];
    }
#pragma unroll
    for (int df = 0; df < 4; ++df)
#pragma unroll
      for (int i = 0; i < 4; ++i)
        oacc[df][i] *= corr[i];

    float psum[4] = {0.f, 0.f, 0.f, 0.f};
    u16 pb[4][4];
#pragma unroll
    for (int nf = 0; nf < 4; ++nf)
#pragma unroll
      for (int i = 0; i < 4; ++i) {
        const float p = exp2f((sv[nf][i] - mrow[i]) * LOG2E);
        psum[i] += p;
        pb[nf][i] = f2b(p);
      }
#pragma unroll
    for (int d = 1; d < 16; d <<= 1)
#pragma unroll
      for (int i = 0; i < 4; ++i)
        psum[i] += __shfl_xor(psum[i], d);
#pragma unroll
    for (int i = 0; i < 4; ++i) lrow[i] += psum[i];

    // P -> per-wave LDS (swizzled), then re-read as A-fragments
    u16* Pw = &Ps[w][0];
#pragma unroll
    for (int nf = 0; nf < 4; ++nf)
#pragma unroll
      for (int i = 0; i < 4; ++i) {
        const int row = (lg << 2) | i;
        const int cb = ((nf * 16 + l16) << 1) ^ ((row & 7) << 4);
        *(u16*)((char*)Pw + row * 128 + cb) = pb[nf][i];
      }
    bf16x8 pa0, pa1;
    {
      const int sw = (l16 & 7) << 4;
      pa0 = *(const bf16x8*)((const char*)Pw + l16 * 128 + ((lg << 4) ^ sw));
      pa1 = *(const bf16x8*)((const char*)Pw + l16 * 128 + ((64 | (lg << 4)) ^ sw));
    }
#pragma unroll
    for (int df = 0; df < 4; ++df) {
      const int row = df * 16 + l16;
      const int sw = (row & 7) << 4;
      bf16x8 vf0 = *(const bf16x8*)((const char*)Vt + row * 128 + ((lg << 4) ^ sw));
      bf16x8 vf1 = *(const bf16x8*)((const char*)Vt + row * 128 + ((64 | (lg << 4)) ^ sw));
      oacc[df] = mfma16(pa0, vf0, oacc[df]);
      oacc[df] = mfma16(pa1, vf1, oacc[df]);
    }
    __syncthreads();
  }

  // epilogue: O /= l, write bf16 to [B,S,H*Dh]
  const int b = bh >> 4, h = bh & 15;
#pragma unroll
  for (int i = 0; i < 4; ++i) {
    const float inv = 1.0f / lrow[i];
    const int q = qblk0 + (w << 4) + (lg << 2) + i;
    u16* orow = Ob + (size_t)(b * SEQ + q) * DEMB + h * DHEAD;
#pragma unroll
    for (int df = 0; df < 4; ++df)
      orow[df * 16 + l16] = f2b(oacc[df][i] * inv);
  }
}

extern "C" void kernel_launch(void* const* d_in, const int* in_sizes, int n_in,
                              void* d_out, int out_size, void* d_ws, size_t ws_size,
                              hipStream_t stream) {
  const float* x = (const float*)d_in[0];
  const float* w_in = (const float*)d_in[1];
  const float* b_in = (const float*)d_in[2];
  const float* w_out = (const float*)d_in[3];
  const float* b_out = (const float*)d_in[4];
  const int* amask = (const int*)d_in[5];
  float* out = (float*)d_out;

  // workspace layout (bf16 elements)
  u16* xb = (u16*)d_ws;                              // 4096*1024
  u16* wib = xb + (size_t)MROWS * DEMB;              // 3072*1024
  u16* wob = wib + (size_t)3 * DEMB * DEMB;          // 1024*1024
  u16* Qb = wob + (size_t)DEMB * DEMB;               // [B,H,S,Dh] = 4M
  u16* Kb = Qb + (size_t)MROWS * DEMB;
  u16* Vb = Kb + (size_t)MROWS * DEMB;
  u16* Ab = xb;  // attention output reuses x-bf16 region (x consumed by QKV GEMM)

  cvt_f32_bf16<<<1024, 256, 0, stream>>>(x, xb, MROWS * DEMB);
  cvt_f32_bf16<<<1024, 256, 0, stream>>>(w_in, wib, 3 * DEMB * DEMB);
  cvt_f32_bf16<<<512, 256, 0, stream>>>(w_out, wob, DEMB * DEMB);

  gemm_nt<0><<<dim3(24, 32), 256, 0, stream>>>(xb, wib, b_in, DEMB, 3 * DEMB,
                                               Qb, Kb, Vb, nullptr);
  attn_fwd<<<dim3(SEQ / 64, 32), 256, 0, stream>>>(Qb, Kb, Vb, Ab, amask);
  gemm_nt<1><<<dim3(8, 32), 256, 0, stream>>>(Ab, wob, b_out, DEMB, DEMB,
                                              nullptr, nullptr, nullptr, out);
}

// Round 3
// 218.302 us; speedup vs baseline: 1.0633x; 1.0633x over previous
//
#include <hip/hip_runtime.h>
#include <stdint.h>

#define DEMB 1024
#define NHEAD 16
#define DHEAD 64
#define SEQ 2048
#define MROWS 4096  // B*S

typedef __bf16 bf16x8 __attribute__((ext_vector_type(8)));
typedef float f32x4 __attribute__((ext_vector_type(4)));
typedef unsigned short u16;

#define LOG2E 1.44269504088896340736f

__device__ __forceinline__ u16 f2b(float f) {
  uint32_t u = __builtin_bit_cast(uint32_t, f);
  u += 0x7fffu + ((u >> 16) & 1u);
  return (u16)(u >> 16);
}

__device__ __forceinline__ f32x4 mfma16(bf16x8 a, bf16x8 b, f32x4 c) {
  return __builtin_amdgcn_mfma_f32_16x16x32_bf16(a, b, c, 0, 0, 0);
}

__device__ __forceinline__ void gload_lds16(const void* g, void* l) {
  __builtin_amdgcn_global_load_lds(
      (__attribute__((address_space(1))) unsigned int*)(g),
      (__attribute__((address_space(3))) unsigned int*)(l), 16, 0, 0);
}

// 2-phase tile barrier: drain this wave's global_load_lds (vmcnt) AND its
// ds_writes (lgkmcnt) before the raw barrier, so after the barrier every
// wave's staging is visible block-wide.
__device__ __forceinline__ void tile_barrier() {
  __builtin_amdgcn_sched_barrier(0);
  asm volatile("s_waitcnt vmcnt(0) lgkmcnt(0)" ::: "memory");
  __builtin_amdgcn_s_barrier();
  __builtin_amdgcn_sched_barrier(0);
}

__global__ void cvt_f32_bf16(const float* __restrict__ src, u16* __restrict__ dst, int n) {
  int idx = (blockIdx.x * blockDim.x + threadIdx.x) * 4;
  const int stride = gridDim.x * blockDim.x * 4;
  for (; idx < n; idx += stride) {
    float4 f = *(const float4*)(src + idx);
    ushort4 o;
    o.x = f2b(f.x); o.y = f2b(f.y); o.z = f2b(f.z); o.w = f2b(f.w);
    *(ushort4*)(dst + idx) = o;
  }
}

// NT GEMM: C[m,n] = sum_k A[m,k]*B[n,k] (+bias[n]).
// BM=BN=128, BK=64, 4 waves (2x2), swizzled LDS via pre-swizzled global src.
// EPI==0: scatter to Q/K/V [B,H,S,Dh] bf16 (Q pre-scaled by 1/8, exact pow2).
// EPI==1: write fp32 C[m*N+n].
template <int EPI>
__global__ __launch_bounds__(256, 2) void gemm_nt(
    const u16* __restrict__ A, const u16* __restrict__ Bw,
    const float* __restrict__ bias, int K, int N,
    u16* __restrict__ q_out, u16* __restrict__ k_out, u16* __restrict__ v_out,
    float* __restrict__ f_out) {
  __shared__ __align__(16) u16 As[128 * 64];
  __shared__ __align__(16) u16 Bs[128 * 64];
  const int tid = threadIdx.x;
  const int w = tid >> 6;
  const int lane = tid & 63;
  const int wm = w >> 1, wn = w & 1;
  const int m0 = blockIdx.y * 128, n0 = blockIdx.x * 128;
  const int l16 = lane & 15, lg = lane >> 4;
  const int st_row = lane >> 3, st_slot = lane & 7;

  f32x4 acc[4][4] = {};

  for (int k0 = 0; k0 < K; k0 += 64) {
#pragma unroll
    for (int i = 0; i < 4; ++i) {
      const int chunk = (w << 2) | i;
      const int row = (chunk << 3) | st_row;
      const int scol = (st_slot ^ (row & 7)) << 3;
      gload_lds16(A + (size_t)(m0 + row) * K + k0 + scol, (char*)As + (chunk << 10));
      gload_lds16(Bw + (size_t)(n0 + row) * K + k0 + scol, (char*)Bs + (chunk << 10));
    }
    __syncthreads();
#pragma unroll
    for (int ks = 0; ks < 2; ++ks) {
      bf16x8 af[4], bfr[4];
#pragma unroll
      for (int mi = 0; mi < 4; ++mi) {
        const int row = wm * 64 + mi * 16 + l16;
        const int cb = ((ks << 6) | (lg << 4)) ^ ((row & 7) << 4);
        af[mi] = *(const bf16x8*)((const char*)As + row * 128 + cb);
      }
#pragma unroll
      for (int ni = 0; ni < 4; ++ni) {
        const int row = wn * 64 + ni * 16 + l16;
        const int cb = ((ks << 6) | (lg << 4)) ^ ((row & 7) << 4);
        bfr[ni] = *(const bf16x8*)((const char*)Bs + row * 128 + cb);
      }
#pragma unroll
      for (int mi = 0; mi < 4; ++mi)
#pragma unroll
        for (int ni = 0; ni < 4; ++ni)
          acc[mi][ni] = mfma16(af[mi], bfr[ni], acc[mi][ni]);
    }
    __syncthreads();
  }

#pragma unroll
  for (int ni = 0; ni < 4; ++ni) {
    const int n = n0 + wn * 64 + ni * 16 + l16;
    const float bv = bias[n];
    if (EPI == 0) {
      const int part = n >> 10;
      const int hh = (n >> 6) & 15;
      const int dh = n & 63;
      const float scl = (part == 0) ? 0.125f : 1.0f;  // fold 1/sqrt(Dh) into Q
      u16* dst = (part == 0) ? q_out : (part == 1) ? k_out : v_out;
#pragma unroll
      for (int mi = 0; mi < 4; ++mi) {
#pragma unroll
        for (int i = 0; i < 4; ++i) {
          const int m = m0 + wm * 64 + mi * 16 + (lg << 2) + i;
          const int bq = m >> 11, s = m & 2047;
          dst[((size_t)((bq << 4) | hh) * SEQ + s) * DHEAD + dh] = f2b((acc[mi][ni][i] + bv) * scl);
        }
      }
    } else {
#pragma unroll
      for (int mi = 0; mi < 4; ++mi)
#pragma unroll
        for (int i = 0; i < 4; ++i) {
          const int m = m0 + wm * 64 + mi * 16 + (lg << 2) + i;
          f_out[(size_t)m * N + n] = acc[mi][ni][i] + bv;
        }
    }
  }
}

// ---- attention ----
// K tile [64][64] staged with XOR swizzle (pre-swizzled global source).
__device__ __forceinline__ void stage_k(const u16* __restrict__ Kb, size_t base,
                                        int jt, u16* Ks, int w, int lane) {
  const int st_row = lane >> 3, st_slot = lane & 7;
#pragma unroll
  for (int i = 0; i < 2; ++i) {
    const int chunk = (w << 1) | i;
    const int row = (chunk << 3) | st_row;
    const int scol = (st_slot ^ (row & 7)) << 3;
    gload_lds16(Kb + base + (size_t)(jt * 64 + row) * DHEAD + scol, (char*)Ks + (chunk << 10));
  }
}

// V transpose into swizzled LDS Vt[d][kv] (proven round-1 path): thread holds
// V[vr][c0..c0+7] in regs, scatters 8 scalar writes per half.
__device__ __forceinline__ void write_vt(u16* Vt, uint4 va, uint4 vb, int tid) {
  const int c0 = (tid & 7) << 3;
  const int vr0 = tid >> 3;        // kv row for va
  const int vr1 = 32 + (tid >> 3); // kv row for vb
  const u16* pa = (const u16*)&va;
  const u16* pb = (const u16*)&vb;
#pragma unroll
  for (int e = 0; e < 8; ++e) {
    const int rt = c0 + e;  // d (row of Vt)
    const int sw = (rt & 7) << 4;
    *(u16*)((char*)Vt + rt * 128 + ((vr0 << 1) ^ sw)) = pa[e];
    *(u16*)((char*)Vt + rt * 128 + ((vr1 << 1) ^ sw)) = pb[e];
  }
}

__global__ __launch_bounds__(256, 4) void attn_fwd(
    const u16* __restrict__ Qb, const u16* __restrict__ Kb,
    const u16* __restrict__ Vb, u16* __restrict__ Ob,
    const int* __restrict__ amask) {
  __shared__ __align__(16) u16 Ks[2][64 * 64];
  __shared__ __align__(16) u16 Vt[2][64 * 64];
  __shared__ __align__(16) u16 Ps[4][16 * 64];
  const int tid = threadIdx.x;
  const int w = tid >> 6, lane = tid & 63;
  const int l16 = lane & 15, lg = lane >> 4;
  const int qi = blockIdx.x, bh = blockIdx.y;
  const int qblk0 = qi * 64;
  const size_t base = (size_t)bh * (SEQ * DHEAD);
  const bool causal = (amask[0] != 0);
  const int ntiles = causal ? (qi + 1) : (SEQ / 64);

  // Q fragments (Q already scaled by 1/8 in GEMM epilogue)
  bf16x8 qf[2];
  {
    const u16* qp = Qb + base + (size_t)(qblk0 + w * 16 + l16) * DHEAD + (lg << 3);
    qf[0] = *(const bf16x8*)qp;
    qf[1] = *(const bf16x8*)(qp + 32);
  }

  float mrow[4] = {-1e30f, -1e30f, -1e30f, -1e30f};
  float lrow[4] = {0.f, 0.f, 0.f, 0.f};
  f32x4 oacc[4] = {};

  const int vcol = (tid & 7) << 3;
  const int vrow = tid >> 3;

  // prologue: stage tile 0 (K via gload_lds, V via regs -> transposed ds_write)
  stage_k(Kb, base, 0, Ks[0], w, lane);
  {
    uint4 va = *(const uint4*)(Vb + base + (size_t)vrow * DHEAD + vcol);
    uint4 vb2 = *(const uint4*)(Vb + base + (size_t)(32 + vrow) * DHEAD + vcol);
    write_vt(Vt[0], va, vb2, tid);
  }
  tile_barrier();

  int cur = 0;
  for (int j = 0; j < ntiles; ++j) {
    const u16* Kcur = Ks[cur];
    const u16* Vcur = Vt[cur];
    const bool pre = (j + 1 < ntiles);
    uint4 vna = {}, vnb = {};
    if (pre) {  // issue next tile's loads early; latency hides under compute
      stage_k(Kb, base, j + 1, Ks[cur ^ 1], w, lane);
      const u16* vsrc = Vb + base + (size_t)(j + 1) * 64 * DHEAD;
      vna = *(const uint4*)(vsrc + (size_t)vrow * DHEAD + vcol);
      vnb = *(const uint4*)(vsrc + (size_t)(32 + vrow) * DHEAD + vcol);
    }

    // S = Q K^T (per wave: 16 q-rows x 64 kv)
    f32x4 sv[4];
    __builtin_amdgcn_s_setprio(1);
#pragma unroll
    for (int nf = 0; nf < 4; ++nf) {
      const int row = nf * 16 + l16;
      const int sw = (row & 7) << 4;
      bf16x8 kf0 = *(const bf16x8*)((const char*)Kcur + row * 128 + ((lg << 4) ^ sw));
      bf16x8 kf1 = *(const bf16x8*)((const char*)Kcur + row * 128 + ((64 | (lg << 4)) ^ sw));
      f32x4 s = {};
      s = mfma16(qf[0], kf0, s);
      s = mfma16(qf[1], kf1, s);
      sv[nf] = s;
    }
    __builtin_amdgcn_s_setprio(0);

    if (causal && (j == qi)) {
#pragma unroll
      for (int nf = 0; nf < 4; ++nf)
#pragma unroll
        for (int i = 0; i < 4; ++i) {
          const int qrow = (w << 4) + (lg << 2) + i;
          const int col = nf * 16 + l16;
          if (col > qrow) sv[nf][i] = -1e30f;
        }
    }

    // row max over this tile (in-reg + 16-lane shuffle tree)
    float tmax[4];
#pragma unroll
    for (int i = 0; i < 4; ++i)
      tmax[i] = fmaxf(fmaxf(sv[0][i], sv[1][i]), fmaxf(sv[2][i], sv[3][i]));
#pragma unroll
    for (int d = 1; d < 16; d <<= 1)
#pragma unroll
      for (int i = 0; i < 4; ++i)
        tmax[i] = fmaxf(tmax[i], __shfl_xor(tmax[i], d));

    // defer-max (T13): only rescale when some row's max grew by > 8
    int grow = 0;
#pragma unroll
    for (int i = 0; i < 4; ++i) grow |= (tmax[i] > mrow[i] + 8.0f) ? 1 : 0;
    if (__any(grow)) {
#pragma unroll
      for (int i = 0; i < 4; ++i) {
        const float mnew = fmaxf(mrow[i], tmax[i]);
        const float corr = exp2f((mrow[i] - mnew) * LOG2E);
        mrow[i] = mnew;
        lrow[i] *= corr;
#pragma unroll
        for (int df = 0; df < 4; ++df) oacc[df][i] *= corr;
      }
    }

    float psum[4] = {0.f, 0.f, 0.f, 0.f};
    u16 pb[4][4];
#pragma unroll
    for (int nf = 0; nf < 4; ++nf)
#pragma unroll
      for (int i = 0; i < 4; ++i) {
        const float p = exp2f((sv[nf][i] - mrow[i]) * LOG2E);
        psum[i] += p;
        pb[nf][i] = f2b(p);
      }
#pragma unroll
    for (int d = 1; d < 16; d <<= 1)
#pragma unroll
      for (int i = 0; i < 4; ++i)
        psum[i] += __shfl_xor(psum[i], d);
#pragma unroll
    for (int i = 0; i < 4; ++i) lrow[i] += psum[i];

    // P -> per-wave LDS (swizzled), re-read as A-fragments
    u16* Pw = &Ps[w][0];
#pragma unroll
    for (int nf = 0; nf < 4; ++nf)
#pragma unroll
      for (int i = 0; i < 4; ++i) {
        const int row = (lg << 2) | i;
        const int cb = ((nf * 16 + l16) << 1) ^ ((row & 7) << 4);
        *(u16*)((char*)Pw + row * 128 + cb) = pb[nf][i];
      }
    bf16x8 pa0, pa1;
    {
      const int sw = (l16 & 7) << 4;
      pa0 = *(const bf16x8*)((const char*)Pw + l16 * 128 + ((lg << 4) ^ sw));
      pa1 = *(const bf16x8*)((const char*)Pw + l16 * 128 + ((64 | (lg << 4)) ^ sw));
    }

    // PV from transposed V tile (proven swizzled bf16x8 reads)
    __builtin_amdgcn_s_setprio(1);
#pragma unroll
    for (int df = 0; df < 4; ++df) {
      const int row = df * 16 + l16;
      const int sw = (row & 7) << 4;
      bf16x8 vf0 = *(const bf16x8*)((const char*)Vcur + row * 128 + ((lg << 4) ^ sw));
      bf16x8 vf1 = *(const bf16x8*)((const char*)Vcur + row * 128 + ((64 | (lg << 4)) ^ sw));
      oacc[df] = mfma16(pa0, vf0, oacc[df]);
      oacc[df] = mfma16(pa1, vf1, oacc[df]);
    }
    __builtin_amdgcn_s_setprio(0);

    if (pre) {
      write_vt(Vt[cur ^ 1], vna, vnb, tid);  // compiler waits vmcnt for vna/vnb
      tile_barrier();
    }
    cur ^= 1;
  }

  // epilogue: O /= l, write bf16 to [B,S,H*Dh]
  const int b = bh >> 4, h = bh & 15;
#pragma unroll
  for (int i = 0; i < 4; ++i) {
    const float inv = 1.0f / lrow[i];
    const int q = qblk0 + (w << 4) + (lg << 2) + i;
    u16* orow = Ob + (size_t)(b * SEQ + q) * DEMB + h * DHEAD;
#pragma unroll
    for (int df = 0; df < 4; ++df)
      orow[df * 16 + l16] = f2b(oacc[df][i] * inv);
  }
}

extern "C" void kernel_launch(void* const* d_in, const int* in_sizes, int n_in,
                              void* d_out, int out_size, void* d_ws, size_t ws_size,
                              hipStream_t stream) {
  const float* x = (const float*)d_in[0];
  const float* w_in = (const float*)d_in[1];
  const float* b_in = (const float*)d_in[2];
  const float* w_out = (const float*)d_in[3];
  const float* b_out = (const float*)d_in[4];
  const int* amask = (const int*)d_in[5];
  float* out = (float*)d_out;

  u16* xb = (u16*)d_ws;
  u16* wib = xb + (size_t)MROWS * DEMB;
  u16* wob = wib + (size_t)3 * DEMB * DEMB;
  u16* Qb = wob + (size_t)DEMB * DEMB;
  u16* Kb = Qb + (size_t)MROWS * DEMB;
  u16* Vb = Kb + (size_t)MROWS * DEMB;
  u16* Ab = xb;  // attn output reuses x-bf16 region

  cvt_f32_bf16<<<1024, 256, 0, stream>>>(x, xb, MROWS * DEMB);
  cvt_f32_bf16<<<1024, 256, 0, stream>>>(w_in, wib, 3 * DEMB * DEMB);
  cvt_f32_bf16<<<512, 256, 0, stream>>>(w_out, wob, DEMB * DEMB);

  gemm_nt<0><<<dim3(24, 32), 256, 0, stream>>>(xb, wib, b_in, DEMB, 3 * DEMB,
                                               Qb, Kb, Vb, nullptr);
  attn_fwd<<<dim3(SEQ / 64, 32), 256, 0, stream>>>(Qb, Kb, Vb, Ab, amask);
  gemm_nt<1><<<dim3(8, 32), 256, 0, stream>>>(Ab, wob, b_out, DEMB, DEMB,
                                              nullptr, nullptr, nullptr, out);
}